// Round 1
// baseline (158.060 us; speedup 1.0000x reference)
//
#include <hip/hip_runtime.h>
#include <hip/hip_bf16.h>

typedef __bf16 bf16_t;
typedef bf16_t bf16x4 __attribute__((ext_vector_type(4)));
typedef bf16_t bf16x8 __attribute__((ext_vector_type(8)));
typedef float f32x4 __attribute__((ext_vector_type(4)));

#define AS1 __attribute__((address_space(1)))
#define AS3 __attribute__((address_space(3)))

__device__ __forceinline__ void gload_lds16(const void* g, void* l) {
    __builtin_amdgcn_global_load_lds((const AS1 void*)g, (AS3 void*)l, 16, 0, 0);
}

__device__ __forceinline__ float sigmoidf_(float v) {
    return 1.0f / (1.0f + __expf(-v));
}

// ---------------- f32 -> bf16 convert ----------------
__global__ __launch_bounds__(256) void k_convert(const float* __restrict__ in,
                                                 bf16_t* __restrict__ out, int n4) {
    int idx = blockIdx.x * blockDim.x + threadIdx.x;
    int stride = gridDim.x * blockDim.x;
    for (int i = idx; i < n4; i += stride) {
        float4 v = ((const float4*)in)[i];
        bf16x4 o;
        o[0] = (bf16_t)v.x; o[1] = (bf16_t)v.y; o[2] = (bf16_t)v.z; o[3] = (bf16_t)v.w;
        ((bf16x4*)out)[i] = o;
    }
}

// ---------------- row sums ----------------
// rows [0,4096): rax[row] = alpha * sum_f A2[row, f]      (f in [0,2048) = ax half)
// rows [4096,5120): rbp[row-4096] = sum_f B2[row-4096, 2048+f]  (= beta*bp half)
__global__ __launch_bounds__(256) void k_rowsum(const bf16_t* __restrict__ A2,
                                                const bf16_t* __restrict__ B2,
                                                const float* __restrict__ pa,
                                                float* __restrict__ rax,
                                                float* __restrict__ rbp) {
    const int row = blockIdx.x;
    const int tid = threadIdx.x;
    const bf16_t* src = (row < 4096) ? (A2 + (long)row * 4096)
                                     : (B2 + (long)(row - 4096) * 4096 + 2048);
    bf16x8 v = *(const bf16x8*)(src + tid * 8);
    float s = 0.f;
#pragma unroll
    for (int j = 0; j < 8; ++j) s += (float)v[j];
#pragma unroll
    for (int off = 32; off > 0; off >>= 1) s += __shfl_down(s, off);
    __shared__ float partial[4];
    if ((tid & 63) == 0) partial[tid >> 6] = s;
    __syncthreads();
    if (tid == 0) {
        float t = partial[0] + partial[1] + partial[2] + partial[3];
        if (row < 4096) rax[row] = pa[0] * t;
        else            rbp[row - 4096] = t;
    }
}

// ---------------- NT GEMM: C[m,n] = sum_k A[m,k]*B[n,k] (both row-major, K contig) ---
// 128x128 tile, BK=64, 256 threads = 4 waves (2x2), each wave 64x64 = 4x4 MFMA frags.
// EPI 0: O2[r, c] = bf16(v*sig(v)); O2[r, halfN+c] = bf16(sig(v))
// EPI 1: O2[r, c] = bf16(theta*v*s + alpha*s); O2[r, halfN+c] = bf16(beta*v*s)
// EPI 2: Of[r, c] = v - rax[r] - rbp[c]
constexpr int BMt = 128, BNt = 128, BKt = 64;

template <int EPI>
__global__ __launch_bounds__(256) void gemm_nt(
    const bf16_t* __restrict__ A, const bf16_t* __restrict__ B, int K, int lda, int ldb,
    bf16_t* __restrict__ O2, int ldo2, int halfN,
    float* __restrict__ Of, int ldof,
    const float* __restrict__ rax, const float* __restrict__ rbp,
    const float* __restrict__ pa, const float* __restrict__ pb, const float* __restrict__ pt) {
    __shared__ bf16_t As[BMt * BKt];
    __shared__ bf16_t Bs[BNt * BKt];

    const int tid = threadIdx.x;
    const int wave = tid >> 6;
    const int lane = tid & 63;
    const int bm = blockIdx.x * BMt;
    const int bn = blockIdx.y * BNt;
    const int wm = (wave >> 1) * 64;
    const int wn = (wave & 1) * 64;

    f32x4 acc[4][4] = {};

    const char* Abytes = (const char*)A;
    const char* Bbytes = (const char*)B;
    char* AsB = (char*)As;
    char* BsB = (char*)Bs;
    const long ldab = (long)lda * 2;
    const long ldbb = (long)ldb * 2;
    const int soff = wave * 4096 + lane * 16;  // per-lane global byte offset base

    for (int k0 = 0; k0 < K; k0 += BKt) {
#pragma unroll
        for (int r = 0; r < 4; ++r) {
            const int off = soff + r * 1024;   // byte offset into the 16KB tile
            const int row = off >> 7;          // 128 B per row (64 bf16)
            const int colb = off & 127;
            const int uoff = wave * 4096 + r * 1024;  // wave-uniform LDS byte offset
            gload_lds16(Abytes + (long)(bm + row) * ldab + (long)k0 * 2 + colb, AsB + uoff);
            gload_lds16(Bbytes + (long)(bn + row) * ldbb + (long)k0 * 2 + colb, BsB + uoff);
        }
        asm volatile("s_waitcnt vmcnt(0)" ::: "memory");
        __syncthreads();

        const int arow = (wm + (lane & 15)) * BKt + ((lane >> 4) << 3);
        const int brow = (wn + (lane & 15)) * BKt + ((lane >> 4) << 3);
#pragma unroll
        for (int kk = 0; kk < BKt; kk += 32) {
            bf16x8 af[4], bfr[4];
#pragma unroll
            for (int i = 0; i < 4; ++i) af[i] = *(const bf16x8*)&As[arow + i * 16 * BKt + kk];
#pragma unroll
            for (int i = 0; i < 4; ++i) bfr[i] = *(const bf16x8*)&Bs[brow + i * 16 * BKt + kk];
#pragma unroll
            for (int i = 0; i < 4; ++i)
#pragma unroll
                for (int j = 0; j < 4; ++j)
                    acc[i][j] = __builtin_amdgcn_mfma_f32_16x16x32_bf16(af[i], bfr[j], acc[i][j], 0, 0, 0);
        }
        __syncthreads();
    }

    // Epilogue. C/D layout (verified m89/m91): col = lane&15, row = (lane>>4)*4 + reg.
    const int er0 = bm + wm + ((lane >> 4) << 2);
    const int ec0 = bn + wn + (lane & 15);

    if constexpr (EPI == 0) {
#pragma unroll
        for (int i = 0; i < 4; ++i)
#pragma unroll
            for (int j = 0; j < 4; ++j)
#pragma unroll
                for (int q = 0; q < 4; ++q) {
                    const int r = er0 + i * 16 + q;
                    const int c = ec0 + j * 16;
                    const float v = acc[i][j][q];
                    const float s = sigmoidf_(v);
                    O2[(long)r * ldo2 + c] = (bf16_t)(v * s);
                    O2[(long)r * ldo2 + halfN + c] = (bf16_t)s;
                }
    } else if constexpr (EPI == 1) {
        const float va = pa[0], vb = pb[0], vt = pt[0];
#pragma unroll
        for (int i = 0; i < 4; ++i)
#pragma unroll
            for (int j = 0; j < 4; ++j)
#pragma unroll
                for (int q = 0; q < 4; ++q) {
                    const int r = er0 + i * 16 + q;
                    const int c = ec0 + j * 16;
                    const float v = acc[i][j][q];
                    const float s = sigmoidf_(v);
                    const float bp = v * s;
                    O2[(long)r * ldo2 + c] = (bf16_t)(vt * bp + va * s);
                    O2[(long)r * ldo2 + halfN + c] = (bf16_t)(vb * bp);
                }
    } else {
#pragma unroll
        for (int i = 0; i < 4; ++i)
#pragma unroll
            for (int j = 0; j < 4; ++j)
#pragma unroll
                for (int q = 0; q < 4; ++q) {
                    const int r = er0 + i * 16 + q;
                    const int c = ec0 + j * 16;
                    Of[(long)r * ldof + c] = acc[i][j][q] - rax[r] - rbp[c];
                }
    }
}

extern "C" void kernel_launch(void* const* d_in, const int* in_sizes, int n_in,
                              void* d_out, int out_size, void* d_ws, size_t ws_size,
                              hipStream_t stream) {
    const float* x = (const float*)d_in[0];       // [4096,1024]
    const float* feats = (const float*)d_in[1];   // [2048,1024]
    const float* protos = (const float*)d_in[2];  // [1024,1024]
    const float* pa = (const float*)d_in[3];
    const float* pb = (const float*)d_in[4];
    const float* pt = (const float*)d_in[5];
    float* out = (float*)d_out;                   // [4096,1024]

    constexpr long Bsz = 4096, D = 1024, F = 2048, P = 1024;

    bf16_t* x16 = (bf16_t*)d_ws;              // 8 MB
    bf16_t* f16 = x16 + Bsz * D;              // 4 MB
    bf16_t* p16 = f16 + F * D;                // 2 MB
    bf16_t* A2 = p16 + P * D;                 // 32 MB  [4096 x 4096] = [ax | sx]
    bf16_t* B2 = A2 + Bsz * 2 * F;            // 8 MB   [1024 x 4096] = [t*bp+a*sp | b*bp]
    float* rax = (float*)(B2 + P * 2 * F);    // 16 KB
    float* rbp = rax + Bsz;                   // 4 KB

    k_convert<<<2048, 256, 0, stream>>>(x, x16, (int)(Bsz * D / 4));
    k_convert<<<1024, 256, 0, stream>>>(feats, f16, (int)(F * D / 4));
    k_convert<<<512, 256, 0, stream>>>(protos, p16, (int)(P * D / 4));

    // GEMM1a: xf = x @ feats^T  [4096 x 2048], K=1024 -> A2 epilogue
    gemm_nt<0><<<dim3(Bsz / 128, F / 128), 256, 0, stream>>>(
        x16, f16, (int)D, (int)D, (int)D, A2, (int)(2 * F), (int)F,
        nullptr, 0, nullptr, nullptr, nullptr, nullptr, nullptr);

    // GEMM1b: pf = protos @ feats^T  [1024 x 2048], K=1024 -> B2 epilogue
    gemm_nt<1><<<dim3(P / 128, F / 128), 256, 0, stream>>>(
        p16, f16, (int)D, (int)D, (int)D, B2, (int)(2 * F), (int)F,
        nullptr, 0, nullptr, nullptr, pa, pb, pt);

    // row sums: rax = alpha * rowsum(ax), rbp = rowsum(beta*bp)
    k_rowsum<<<(unsigned)(Bsz + P), 256, 0, stream>>>(A2, B2, pa, rax, rbp);

    // GEMM2: out = A2 @ B2^T - rax[b] - rbp[p]   [4096 x 1024], K=4096
    gemm_nt<2><<<dim3(Bsz / 128, P / 128), 256, 0, stream>>>(
        A2, B2, (int)(2 * F), (int)(2 * F), (int)(2 * F), nullptr, 0, 0,
        out, (int)P, rax, rbp, nullptr, nullptr, nullptr);
}

// Round 2
// 140.937 us; speedup vs baseline: 1.1215x; 1.1215x over previous
//
#include <hip/hip_runtime.h>
#include <hip/hip_bf16.h>

typedef __bf16 bf16_t;
typedef bf16_t bf16x4 __attribute__((ext_vector_type(4)));
typedef bf16_t bf16x8 __attribute__((ext_vector_type(8)));
typedef float f32x4 __attribute__((ext_vector_type(4)));

#define AS1 __attribute__((address_space(1)))
#define AS3 __attribute__((address_space(3)))

__device__ __forceinline__ void gload_lds16(const void* g, void* l) {
    __builtin_amdgcn_global_load_lds((const AS1 void*)g, (AS3 void*)l, 16, 0, 0);
}

__device__ __forceinline__ float sigmoidf_(float v) {
    return 1.0f / (1.0f + __expf(-v));
}

// ---------------- f32 -> bf16 convert ----------------
__global__ __launch_bounds__(256) void k_convert(const float* __restrict__ in,
                                                 bf16_t* __restrict__ out, int n4) {
    int idx = blockIdx.x * blockDim.x + threadIdx.x;
    int stride = gridDim.x * blockDim.x;
    for (int i = idx; i < n4; i += stride) {
        float4 v = ((const float4*)in)[i];
        bf16x4 o;
        o[0] = (bf16_t)v.x; o[1] = (bf16_t)v.y; o[2] = (bf16_t)v.z; o[3] = (bf16_t)v.w;
        ((bf16x4*)out)[i] = o;
    }
}

// ---------------- row sums ----------------
__global__ __launch_bounds__(256) void k_rowsum(const bf16_t* __restrict__ A2,
                                                const bf16_t* __restrict__ B2,
                                                const float* __restrict__ pa,
                                                float* __restrict__ rax,
                                                float* __restrict__ rbp) {
    const int row = blockIdx.x;
    const int tid = threadIdx.x;
    const bf16_t* src = (row < 4096) ? (A2 + (long)row * 4096)
                                     : (B2 + (long)(row - 4096) * 4096 + 2048);
    bf16x8 v = *(const bf16x8*)(src + tid * 8);
    float s = 0.f;
#pragma unroll
    for (int j = 0; j < 8; ++j) s += (float)v[j];
#pragma unroll
    for (int off = 32; off > 0; off >>= 1) s += __shfl_down(s, off);
    __shared__ float partial[4];
    if ((tid & 63) == 0) partial[tid >> 6] = s;
    __syncthreads();
    if (tid == 0) {
        float t = partial[0] + partial[1] + partial[2] + partial[3];
        if (row < 4096) rax[row] = pa[0] * t;
        else            rbp[row - 4096] = t;
    }
}

// ---------------- split-K reduce + epilogue ----------------
// out[r,c] = sum_s part[s][r,c] - rax[r] - rbp[c];  M=4096, N=1024.
template <int S>
__global__ __launch_bounds__(256) void k_reduce(const float* __restrict__ part,
                                                const float* __restrict__ rax,
                                                const float* __restrict__ rbp,
                                                float* __restrict__ out) {
    const long nv = (long)4096 * 1024 / 4;  // f32x4 elements
    long idx = (long)blockIdx.x * blockDim.x + threadIdx.x;
    const long stride = (long)gridDim.x * blockDim.x;
    for (; idx < nv; idx += stride) {
        const int row = (int)(idx >> 8);          // 256 f32x4 per 1024-wide row
        const int c4 = (int)(idx & 255) << 2;
        f32x4 v = ((const f32x4*)part)[idx];
#pragma unroll
        for (int s = 1; s < S; ++s)
            v += ((const f32x4*)(part + (long)s * 4096 * 1024))[idx];
        const float ra = rax[row];
        const f32x4 rb = *(const f32x4*)&rbp[c4];
        f32x4 o;
#pragma unroll
        for (int j = 0; j < 4; ++j) o[j] = v[j] - ra - rb[j];
        ((f32x4*)out)[idx] = o;
    }
}

// ---------------- NT GEMM: C[m,n] = sum_k A[m,k]*B[n,k] ----------------
// 128x128 tile, BK=64, 256 threads = 4 waves (2x2), each wave 64x64 = 4x4 frags.
// EPI 0: O2[r,c]=bf16(v*sig(v)); O2[r,halfN+c]=bf16(sig(v))
// EPI 1: O2[r,c]=bf16(theta*v*s+alpha*s); O2[r,halfN+c]=bf16(beta*v*s)
// EPI 2: Of[r,c]=v-rax[r]-rbp[c]   (single-shot, no split)
// EPI 3: raw f32 partial write; blockIdx.z selects K-chunk of length K and
//        output slab Of + z*zstride.
constexpr int BMt = 128, BNt = 128, BKt = 64;

template <int EPI>
__global__ __launch_bounds__(256) void gemm_nt(
    const bf16_t* __restrict__ A, const bf16_t* __restrict__ B, int K, int lda, int ldb,
    bf16_t* __restrict__ O2, int ldo2, int halfN,
    float* __restrict__ Of, int ldof, long zstride,
    const float* __restrict__ rax, const float* __restrict__ rbp,
    const float* __restrict__ pa, const float* __restrict__ pb, const float* __restrict__ pt) {
    __shared__ bf16_t As[BMt * BKt];
    __shared__ bf16_t Bs[BNt * BKt];

    const int tid = threadIdx.x;
    const int wave = tid >> 6;
    const int lane = tid & 63;
    const int bm = blockIdx.x * BMt;
    const int bn = blockIdx.y * BNt;
    const int wm = (wave >> 1) * 64;
    const int wn = (wave & 1) * 64;
    const int kbeg = blockIdx.z * K;
    if constexpr (EPI == 3) Of += (long)blockIdx.z * zstride;

    f32x4 acc[4][4] = {};

    const char* Abytes = (const char*)A;
    const char* Bbytes = (const char*)B;
    char* AsB = (char*)As;
    char* BsB = (char*)Bs;
    const long ldab = (long)lda * 2;
    const long ldbb = (long)ldb * 2;
    const int soff = wave * 4096 + lane * 16;

    for (int k0 = kbeg; k0 < kbeg + K; k0 += BKt) {
#pragma unroll
        for (int r = 0; r < 4; ++r) {
            const int off = soff + r * 1024;
            const int row = off >> 7;
            const int colb = off & 127;
            const int uoff = wave * 4096 + r * 1024;
            gload_lds16(Abytes + (long)(bm + row) * ldab + (long)k0 * 2 + colb, AsB + uoff);
            gload_lds16(Bbytes + (long)(bn + row) * ldbb + (long)k0 * 2 + colb, BsB + uoff);
        }
        asm volatile("s_waitcnt vmcnt(0)" ::: "memory");
        __syncthreads();

        const int arow = (wm + (lane & 15)) * BKt + ((lane >> 4) << 3);
        const int brow = (wn + (lane & 15)) * BKt + ((lane >> 4) << 3);
#pragma unroll
        for (int kk = 0; kk < BKt; kk += 32) {
            bf16x8 af[4], bfr[4];
#pragma unroll
            for (int i = 0; i < 4; ++i) af[i] = *(const bf16x8*)&As[arow + i * 16 * BKt + kk];
#pragma unroll
            for (int i = 0; i < 4; ++i) bfr[i] = *(const bf16x8*)&Bs[brow + i * 16 * BKt + kk];
#pragma unroll
            for (int i = 0; i < 4; ++i)
#pragma unroll
                for (int j = 0; j < 4; ++j)
                    acc[i][j] = __builtin_amdgcn_mfma_f32_16x16x32_bf16(af[i], bfr[j], acc[i][j], 0, 0, 0);
        }
        __syncthreads();
    }

    // C/D layout (verified m89/m91): col = lane&15, row = (lane>>4)*4 + reg.
    const int er0 = bm + wm + ((lane >> 4) << 2);
    const int ec0 = bn + wn + (lane & 15);

    if constexpr (EPI == 0) {
#pragma unroll
        for (int i = 0; i < 4; ++i)
#pragma unroll
            for (int j = 0; j < 4; ++j)
#pragma unroll
                for (int q = 0; q < 4; ++q) {
                    const int r = er0 + i * 16 + q;
                    const int c = ec0 + j * 16;
                    const float v = acc[i][j][q];
                    const float s = sigmoidf_(v);
                    O2[(long)r * ldo2 + c] = (bf16_t)(v * s);
                    O2[(long)r * ldo2 + halfN + c] = (bf16_t)s;
                }
    } else if constexpr (EPI == 1) {
        const float va = pa[0], vb = pb[0], vt = pt[0];
#pragma unroll
        for (int i = 0; i < 4; ++i)
#pragma unroll
            for (int j = 0; j < 4; ++j)
#pragma unroll
                for (int q = 0; q < 4; ++q) {
                    const int r = er0 + i * 16 + q;
                    const int c = ec0 + j * 16;
                    const float v = acc[i][j][q];
                    const float s = sigmoidf_(v);
                    const float bp = v * s;
                    O2[(long)r * ldo2 + c] = (bf16_t)(vt * bp + va * s);
                    O2[(long)r * ldo2 + halfN + c] = (bf16_t)(vb * bp);
                }
    } else if constexpr (EPI == 2) {
#pragma unroll
        for (int i = 0; i < 4; ++i)
#pragma unroll
            for (int j = 0; j < 4; ++j)
#pragma unroll
                for (int q = 0; q < 4; ++q) {
                    const int r = er0 + i * 16 + q;
                    const int c = ec0 + j * 16;
                    Of[(long)r * ldof + c] = acc[i][j][q] - rax[r] - rbp[c];
                }
    } else {
#pragma unroll
        for (int i = 0; i < 4; ++i)
#pragma unroll
            for (int j = 0; j < 4; ++j)
#pragma unroll
                for (int q = 0; q < 4; ++q) {
                    const int r = er0 + i * 16 + q;
                    const int c = ec0 + j * 16;
                    Of[(long)r * ldof + c] = acc[i][j][q];
                }
    }
}

extern "C" void kernel_launch(void* const* d_in, const int* in_sizes, int n_in,
                              void* d_out, int out_size, void* d_ws, size_t ws_size,
                              hipStream_t stream) {
    const float* x = (const float*)d_in[0];       // [4096,1024]
    const float* feats = (const float*)d_in[1];   // [2048,1024]
    const float* protos = (const float*)d_in[2];  // [1024,1024]
    const float* pa = (const float*)d_in[3];
    const float* pb = (const float*)d_in[4];
    const float* pt = (const float*)d_in[5];
    float* out = (float*)d_out;                   // [4096,1024]

    constexpr long Bsz = 4096, D = 1024, F = 2048, P = 1024;

    bf16_t* x16 = (bf16_t*)d_ws;              // 8 MB
    bf16_t* f16 = x16 + Bsz * D;              // 4 MB
    bf16_t* p16 = f16 + F * D;                // 2 MB
    bf16_t* A2 = p16 + P * D;                 // 32 MB  [4096 x 4096] = [ax | sx]
    bf16_t* B2 = A2 + Bsz * 2 * F;            // 8 MB   [1024 x 4096] = [t*bp+a*sp | b*bp]
    float* rax = (float*)(B2 + P * 2 * F);    // 16 KB
    float* rbp = rax + Bsz;                   // 4 KB
    float* part = rbp + P;                    // split-K partials, 16 MB each

    const size_t base_bytes = (size_t)((char*)part - (char*)d_ws);
    const size_t slab = (size_t)Bsz * P * 4;  // 16 MB
    int split = 1;
    if (ws_size >= base_bytes + 4 * slab) split = 4;
    else if (ws_size >= base_bytes + 2 * slab) split = 2;

    k_convert<<<2048, 256, 0, stream>>>(x, x16, (int)(Bsz * D / 4));
    k_convert<<<1024, 256, 0, stream>>>(feats, f16, (int)(F * D / 4));
    k_convert<<<512, 256, 0, stream>>>(protos, p16, (int)(P * D / 4));

    // GEMM1a: xf = x @ feats^T  [4096 x 2048], K=1024 -> A2 epilogue
    gemm_nt<0><<<dim3(Bsz / 128, F / 128), 256, 0, stream>>>(
        x16, f16, (int)D, (int)D, (int)D, A2, (int)(2 * F), (int)F,
        nullptr, 0, 0, nullptr, nullptr, nullptr, nullptr, nullptr);

    // GEMM1b: pf = protos @ feats^T  [1024 x 2048], K=1024 -> B2 epilogue
    gemm_nt<1><<<dim3(P / 128, F / 128), 256, 0, stream>>>(
        p16, f16, (int)D, (int)D, (int)D, B2, (int)(2 * F), (int)F,
        nullptr, 0, 0, nullptr, nullptr, pa, pb, pt);

    // row sums: rax = alpha * rowsum(ax), rbp = rowsum(beta*bp)
    k_rowsum<<<(unsigned)(Bsz + P), 256, 0, stream>>>(A2, B2, pa, rax, rbp);

    // GEMM2: out = A2 @ B2^T - rax[b] - rbp[p]   [4096 x 1024], K=4096
    if (split == 1) {
        gemm_nt<2><<<dim3(Bsz / 128, P / 128), 256, 0, stream>>>(
            A2, B2, (int)(2 * F), (int)(2 * F), (int)(2 * F), nullptr, 0, 0,
            out, (int)P, 0, rax, rbp, nullptr, nullptr, nullptr);
    } else {
        const int kper = (int)(2 * F) / split;
        gemm_nt<3><<<dim3(Bsz / 128, P / 128, split), 256, 0, stream>>>(
            A2, B2, kper, (int)(2 * F), (int)(2 * F), nullptr, 0, 0,
            part, (int)P, (long)Bsz * P, nullptr, nullptr, nullptr, nullptr, nullptr);
        if (split == 4)
            k_reduce<4><<<2048, 256, 0, stream>>>(part, rax, rbp, out);
        else
            k_reduce<2><<<2048, 256, 0, stream>>>(part, rax, rbp, out);
    }
}

// Round 3
// 137.617 us; speedup vs baseline: 1.1486x; 1.0241x over previous
//
#include <hip/hip_runtime.h>
#include <hip/hip_bf16.h>

typedef __bf16 bf16_t;
typedef bf16_t bf16x4 __attribute__((ext_vector_type(4)));
typedef bf16_t bf16x8 __attribute__((ext_vector_type(8)));
typedef float f32x4 __attribute__((ext_vector_type(4)));

#define AS1 __attribute__((address_space(1)))
#define AS3 __attribute__((address_space(3)))

__device__ __forceinline__ void gload_lds16(const void* g, void* l) {
    __builtin_amdgcn_global_load_lds((const AS1 void*)g, (AS3 void*)l, 16, 0, 0);
}

__device__ __forceinline__ float sigmoidf_(float v) {
    return 1.0f / (1.0f + __expf(-v));
}

// ---------------- f32 -> bf16 convert ----------------
__global__ __launch_bounds__(256) void k_convert(const float* __restrict__ in,
                                                 bf16_t* __restrict__ out, int n4) {
    int idx = blockIdx.x * blockDim.x + threadIdx.x;
    int stride = gridDim.x * blockDim.x;
    for (int i = idx; i < n4; i += stride) {
        float4 v = ((const float4*)in)[i];
        bf16x4 o;
        o[0] = (bf16_t)v.x; o[1] = (bf16_t)v.y; o[2] = (bf16_t)v.z; o[3] = (bf16_t)v.w;
        ((bf16x4*)out)[i] = o;
    }
}

// ---------------- row sums ----------------
__global__ __launch_bounds__(256) void k_rowsum(const bf16_t* __restrict__ A2,
                                                const bf16_t* __restrict__ B2,
                                                const float* __restrict__ pa,
                                                float* __restrict__ rax,
                                                float* __restrict__ rbp) {
    const int row = blockIdx.x;
    const int tid = threadIdx.x;
    const bf16_t* src = (row < 4096) ? (A2 + (long)row * 4096)
                                     : (B2 + (long)(row - 4096) * 4096 + 2048);
    bf16x8 v = *(const bf16x8*)(src + tid * 8);
    float s = 0.f;
#pragma unroll
    for (int j = 0; j < 8; ++j) s += (float)v[j];
#pragma unroll
    for (int off = 32; off > 0; off >>= 1) s += __shfl_down(s, off);
    __shared__ float partial[4];
    if ((tid & 63) == 0) partial[tid >> 6] = s;
    __syncthreads();
    if (tid == 0) {
        float t = partial[0] + partial[1] + partial[2] + partial[3];
        if (row < 4096) rax[row] = pa[0] * t;
        else            rbp[row - 4096] = t;
    }
}

// ---------------- split-K reduce + epilogue ----------------
template <int S>
__global__ __launch_bounds__(256) void k_reduce(const float* __restrict__ part,
                                                const float* __restrict__ rax,
                                                const float* __restrict__ rbp,
                                                float* __restrict__ out) {
    const long nv = (long)4096 * 1024 / 4;
    long idx = (long)blockIdx.x * blockDim.x + threadIdx.x;
    const long stride = (long)gridDim.x * blockDim.x;
    for (; idx < nv; idx += stride) {
        const int row = (int)(idx >> 8);
        const int c4 = (int)(idx & 255) << 2;
        f32x4 v = ((const f32x4*)part)[idx];
#pragma unroll
        for (int s = 1; s < S; ++s)
            v += ((const f32x4*)(part + (long)s * 4096 * 1024))[idx];
        const float ra = rax[row];
        const f32x4 rb = *(const f32x4*)&rbp[c4];
        f32x4 o;
#pragma unroll
        for (int j = 0; j < 4; ++j) o[j] = v[j] - ra - rb[j];
        ((f32x4*)out)[idx] = o;
    }
}

// ================= 8-phase 256x256 GEMM (m201-style, plain HIP) =================
// NT GEMM: C[m,n] = sum_k A[m,k]*B[n,k], both row-major bf16, K contiguous.
// 512 threads = 8 waves (2M x 4N); per-wave output 128x64 (8 m-frags x 4 n-frags).
// BK=64 split into two 32-wide k-slices; LDS = 2buf x {A,B} x 2slice x 16KB = 128KB.
// LDS slice layout: row-major [256 rows][64B], XOR-swizzled: byte ^= ((byte>>9)&1)<<5
// (bank-conflict fix, T2). global_load_lds writes linearly -> inverse swizzle applied
// to the per-lane GLOBAL source address (rule #21: both sides same involution).
// Counted vmcnt(4) twice per K-tile (phases 1 and 3), never 0 in main loop (T4).
// EPI 0: A2 sigmoid pack;  EPI 3: raw f32 partial (split-K, slab bz*zstride).
constexpr int SLICE = 16384;

template <int EPI>
__global__ __launch_bounds__(512, 2) void gemm8p(
    const bf16_t* __restrict__ A, const bf16_t* __restrict__ B,
    int NT, long ldab, long ldbb,
    bf16_t* __restrict__ O2, int ldo2, int halfN,
    float* __restrict__ Of, int ldof, long zstride) {
    __shared__ char lds[131072];
    const int tid = threadIdx.x;
    const int wave = tid >> 6, lane = tid & 63;
    const int wm = wave >> 2, wn = wave & 3;

    // bijective XCD swizzle (nwg % 8 == 0 in all our launches)
    const int gx = gridDim.x, gy = gridDim.y;
    const int o = blockIdx.x + gx * (blockIdx.y + gy * blockIdx.z);
    const int cpx = (gx * gy * (int)gridDim.z) >> 3;
    const int v = (o & 7) * cpx + (o >> 3);
    const int bx = v % gx;
    const int rem = v / gx;
    const int by = rem % gy;
    const int bz = rem / gy;

    const long bm = (long)bx * 256, bn = (long)by * 256;
    const int kb0 = bz * NT * 64;  // element offset of this z-slice's K range
    const char* Ab = (const char*)A + bm * ldab;
    const char* Bb = (const char*)B + bn * ldbb;
    if constexpr (EPI == 3) Of += (long)bz * zstride;

    // per-lane swizzled LDS read offsets (within a 16KB slice)
    const int swzcb = ((lane >> 4) << 4) ^ (((lane >> 3) & 1) << 5);
    const int base_a = (wm * 128 + (lane & 15)) * 64 + swzcb;
    const int base_b = (wn * 64 + (lane & 15)) * 64 + swzcb;

    f32x4 acc[8][4] = {};
    bf16x8 bfrag[4];

    // stage one 16KB k-slice: 2 x gload_lds16 per thread, linear LDS dest,
    // inverse-swizzled global source.
    auto STAGE = [&](const char* gb, long ld, int kbyte, int ldsoff) {
#pragma unroll
        for (int j = 0; j < 2; ++j) {
            const int oo = (j * 512 + tid) << 4;
            const int r = oo >> 6;
            const int cb = (oo & 63) ^ (((oo >> 9) & 1) << 5);
            gload_lds16(gb + (long)r * ld + kbyte + cb, lds + ldsoff + (oo & ~1023));
        }
    };

#define KB(t, s) ((kb0 + (t) * 64 + (s) * 32) * 2)
#define LOFF(b, ab, s) ((((b) * 2 + (ab)) * 2 + (s)) * SLICE)
#define VM4 asm volatile("s_waitcnt vmcnt(4)" ::: "memory")
#define VM0 asm volatile("s_waitcnt vmcnt(0)" ::: "memory")

#define PHASE(Sl, QA, RB, PFSTMT, WAITSTMT)                                     \
    do {                                                                        \
        const int sA = LOFF(cur, 0, Sl);                                        \
        const int sB = LOFF(cur, 1, Sl);                                        \
        bf16x8 af[4];                                                           \
        _Pragma("unroll") for (int f = 0; f < 4; ++f)                           \
            af[f] = *(const bf16x8*)(lds + sA + base_a + (QA * 4 + f) * 1024);  \
        if (RB) {                                                               \
            _Pragma("unroll") for (int g = 0; g < 4; ++g)                       \
                bfrag[g] = *(const bf16x8*)(lds + sB + base_b + g * 1024);      \
        }                                                                       \
        PFSTMT;                                                                 \
        __builtin_amdgcn_sched_barrier(0);                                      \
        __builtin_amdgcn_s_barrier();                                           \
        __builtin_amdgcn_s_setprio(1);                                          \
        _Pragma("unroll") for (int f = 0; f < 4; ++f)                           \
            _Pragma("unroll") for (int g = 0; g < 4; ++g)                       \
                acc[QA * 4 + f][g] = __builtin_amdgcn_mfma_f32_16x16x32_bf16(   \
                    af[f], bfrag[g], acc[QA * 4 + f][g], 0, 0, 0);              \
        __builtin_amdgcn_s_setprio(0);                                          \
        __builtin_amdgcn_sched_barrier(0);                                      \
        WAITSTMT;                                                               \
        __builtin_amdgcn_s_barrier();                                           \
    } while (0)

    // prologue: stage tile 0 (A s0, B s0 oldest -> drained by vmcnt(4))
    int cur = 0;
    STAGE(Ab, ldab, KB(0, 0), LOFF(0, 0, 0));
    STAGE(Bb, ldbb, KB(0, 0), LOFF(0, 1, 0));
    STAGE(Ab, ldab, KB(0, 1), LOFF(0, 0, 1));
    STAGE(Bb, ldbb, KB(0, 1), LOFF(0, 1, 1));
    VM4;
    __builtin_amdgcn_s_barrier();

    for (int t = 0; t < NT - 1; ++t) {
        const int nb = cur ^ 1;
        PHASE(0, 0, 1, STAGE(Ab, ldab, KB(t + 1, 0), LOFF(nb, 0, 0)), );
        PHASE(0, 1, 0, STAGE(Bb, ldbb, KB(t + 1, 0), LOFF(nb, 1, 0)), VM4);
        PHASE(1, 0, 1, STAGE(Ab, ldab, KB(t + 1, 1), LOFF(nb, 0, 1)), );
        PHASE(1, 1, 0, STAGE(Bb, ldbb, KB(t + 1, 1), LOFF(nb, 1, 1)), VM4);
        cur = nb;
    }
    // peeled last tile: no prefetch; drain the last in-flight pair before s1 reads
    PHASE(0, 0, 1, , );
    PHASE(0, 1, 0, , VM0);
    PHASE(1, 0, 1, , );
    PHASE(1, 1, 0, , );

#undef PHASE
#undef KB
#undef LOFF
#undef VM4
#undef VM0

    // epilogue. C/D layout: col = lane&15, row = (lane>>4)*4 + q (m89/m91).
    const int er = (lane >> 4) << 2;
    const int ec = lane & 15;
    if constexpr (EPI == 0) {
#pragma unroll
        for (int fg = 0; fg < 8; ++fg)
#pragma unroll
            for (int g = 0; g < 4; ++g)
#pragma unroll
                for (int q = 0; q < 4; ++q) {
                    const long r = bm + wm * 128 + fg * 16 + er + q;
                    const long c = bn + wn * 64 + g * 16 + ec;
                    const float vv = acc[fg][g][q];
                    const float s = sigmoidf_(vv);
                    O2[r * ldo2 + c] = (bf16_t)(vv * s);
                    O2[r * ldo2 + halfN + c] = (bf16_t)s;
                }
    } else {
#pragma unroll
        for (int fg = 0; fg < 8; ++fg)
#pragma unroll
            for (int g = 0; g < 4; ++g)
#pragma unroll
                for (int q = 0; q < 4; ++q) {
                    const long r = bm + wm * 128 + fg * 16 + er + q;
                    const long c = bn + wn * 64 + g * 16 + ec;
                    Of[r * ldof + c] = acc[fg][g][q];
                }
    }
}

// ---------------- legacy 128x128 m97-style GEMM (GEMM1b + fallback) ----------------
constexpr int BMt = 128, BNt = 128, BKt = 64;

template <int EPI>
__global__ __launch_bounds__(256) void gemm_nt(
    const bf16_t* __restrict__ A, const bf16_t* __restrict__ B, int K, int lda, int ldb,
    bf16_t* __restrict__ O2, int ldo2, int halfN,
    float* __restrict__ Of, int ldof,
    const float* __restrict__ rax, const float* __restrict__ rbp,
    const float* __restrict__ pa, const float* __restrict__ pb, const float* __restrict__ pt) {
    __shared__ bf16_t As[BMt * BKt];
    __shared__ bf16_t Bs[BNt * BKt];

    const int tid = threadIdx.x;
    const int wave = tid >> 6;
    const int lane = tid & 63;
    const int bm = blockIdx.x * BMt;
    const int bn = blockIdx.y * BNt;
    const int wm = (wave >> 1) * 64;
    const int wn = (wave & 1) * 64;

    f32x4 acc[4][4] = {};

    const char* Abytes = (const char*)A;
    const char* Bbytes = (const char*)B;
    char* AsB = (char*)As;
    char* BsB = (char*)Bs;
    const long ldab = (long)lda * 2;
    const long ldbb = (long)ldb * 2;
    const int soff = wave * 4096 + lane * 16;

    for (int k0 = 0; k0 < K; k0 += BKt) {
#pragma unroll
        for (int r = 0; r < 4; ++r) {
            const int off = soff + r * 1024;
            const int row = off >> 7;
            const int colb = off & 127;
            const int uoff = wave * 4096 + r * 1024;
            gload_lds16(Abytes + (long)(bm + row) * ldab + (long)k0 * 2 + colb, AsB + uoff);
            gload_lds16(Bbytes + (long)(bn + row) * ldbb + (long)k0 * 2 + colb, BsB + uoff);
        }
        asm volatile("s_waitcnt vmcnt(0)" ::: "memory");
        __syncthreads();

        const int arow = (wm + (lane & 15)) * BKt + ((lane >> 4) << 3);
        const int brow = (wn + (lane & 15)) * BKt + ((lane >> 4) << 3);
#pragma unroll
        for (int kk = 0; kk < BKt; kk += 32) {
            bf16x8 af[4], bfr[4];
#pragma unroll
            for (int i = 0; i < 4; ++i) af[i] = *(const bf16x8*)&As[arow + i * 16 * BKt + kk];
#pragma unroll
            for (int i = 0; i < 4; ++i) bfr[i] = *(const bf16x8*)&Bs[brow + i * 16 * BKt + kk];
#pragma unroll
            for (int i = 0; i < 4; ++i)
#pragma unroll
                for (int j = 0; j < 4; ++j)
                    acc[i][j] = __builtin_amdgcn_mfma_f32_16x16x32_bf16(af[i], bfr[j], acc[i][j], 0, 0, 0);
        }
        __syncthreads();
    }

    const int er0 = bm + wm + ((lane >> 4) << 2);
    const int ec0 = bn + wn + (lane & 15);

    if constexpr (EPI == 1) {
        const float va = pa[0], vb = pb[0], vt = pt[0];
#pragma unroll
        for (int i = 0; i < 4; ++i)
#pragma unroll
            for (int j = 0; j < 4; ++j)
#pragma unroll
                for (int q = 0; q < 4; ++q) {
                    const int r = er0 + i * 16 + q;
                    const int c = ec0 + j * 16;
                    const float v = acc[i][j][q];
                    const float s = sigmoidf_(v);
                    const float bp = v * s;
                    O2[(long)r * ldo2 + c] = (bf16_t)(vt * bp + va * s);
                    O2[(long)r * ldo2 + halfN + c] = (bf16_t)(vb * bp);
                }
    } else if constexpr (EPI == 2) {
#pragma unroll
        for (int i = 0; i < 4; ++i)
#pragma unroll
            for (int j = 0; j < 4; ++j)
#pragma unroll
                for (int q = 0; q < 4; ++q) {
                    const int r = er0 + i * 16 + q;
                    const int c = ec0 + j * 16;
                    Of[(long)r * ldof + c] = acc[i][j][q] - rax[r] - rbp[c];
                }
    } else {  // EPI == 0 (fallback GEMM1a)
#pragma unroll
        for (int i = 0; i < 4; ++i)
#pragma unroll
            for (int j = 0; j < 4; ++j)
#pragma unroll
                for (int q = 0; q < 4; ++q) {
                    const int r = er0 + i * 16 + q;
                    const int c = ec0 + j * 16;
                    const float v = acc[i][j][q];
                    const float s = sigmoidf_(v);
                    O2[(long)r * ldo2 + c] = (bf16_t)(v * s);
                    O2[(long)r * ldo2 + halfN + c] = (bf16_t)s;
                }
    }
}

extern "C" void kernel_launch(void* const* d_in, const int* in_sizes, int n_in,
                              void* d_out, int out_size, void* d_ws, size_t ws_size,
                              hipStream_t stream) {
    const float* x = (const float*)d_in[0];       // [4096,1024]
    const float* feats = (const float*)d_in[1];   // [2048,1024]
    const float* protos = (const float*)d_in[2];  // [1024,1024]
    const float* pa = (const float*)d_in[3];
    const float* pb = (const float*)d_in[4];
    const float* pt = (const float*)d_in[5];
    float* out = (float*)d_out;                   // [4096,1024]

    constexpr long Bsz = 4096, D = 1024, F = 2048, P = 1024;

    bf16_t* x16 = (bf16_t*)d_ws;              // 8 MB
    bf16_t* f16 = x16 + Bsz * D;              // 4 MB
    bf16_t* p16 = f16 + F * D;                // 2 MB
    bf16_t* A2 = p16 + P * D;                 // 32 MB  [4096 x 4096] = [ax | sx]
    bf16_t* B2 = A2 + Bsz * 2 * F;            // 8 MB   [1024 x 4096] = [t*bp+a*sp | b*bp]
    float* rax = (float*)(B2 + P * 2 * F);    // 16 KB
    float* rbp = rax + Bsz;                   // 4 KB
    float* part = rbp + P;                    // split-K partials, 16 MB each

    const size_t base_bytes = (size_t)((char*)part - (char*)d_ws);
    const size_t slab = (size_t)Bsz * P * 4;  // 16 MB
    const bool split4 = ws_size >= base_bytes + 4 * slab;

    k_convert<<<2048, 256, 0, stream>>>(x, x16, (int)(Bsz * D / 4));
    k_convert<<<1024, 256, 0, stream>>>(feats, f16, (int)(F * D / 4));
    k_convert<<<512, 256, 0, stream>>>(protos, p16, (int)(P * D / 4));

    // GEMM1a: xf = x @ feats^T [4096 x 2048], K=1024 -> A2 = [ax | sx]
    gemm8p<0><<<dim3(Bsz / 256, F / 256, 1), 512, 0, stream>>>(
        x16, f16, (int)(D / 64), D * 2, D * 2,
        A2, (int)(2 * F), (int)F, nullptr, 0, 0);

    // GEMM1b: pf = protos @ feats^T [1024 x 2048], K=1024 -> B2
    gemm_nt<1><<<dim3(P / 128, F / 128), 256, 0, stream>>>(
        p16, f16, (int)D, (int)D, (int)D, B2, (int)(2 * F), (int)F,
        nullptr, 0, nullptr, nullptr, pa, pb, pt);

    // row sums
    k_rowsum<<<(unsigned)(Bsz + P), 256, 0, stream>>>(A2, B2, pa, rax, rbp);

    // GEMM2: out = A2 @ B2^T - rax[b] - rbp[p]  [4096 x 1024], K=4096
    if (split4) {
        gemm8p<3><<<dim3(Bsz / 256, P / 256, 4), 512, 0, stream>>>(
            A2, B2, (int)(2 * F / 64 / 4), 2 * F * 2, 2 * F * 2,
            nullptr, 0, 0, part, (int)P, (long)Bsz * P);
        k_reduce<4><<<2048, 256, 0, stream>>>(part, rax, rbp, out);
    } else {
        gemm_nt<2><<<dim3(Bsz / 128, P / 128), 256, 0, stream>>>(
            A2, B2, (int)(2 * F), (int)(2 * F), (int)(2 * F), nullptr, 0, 0,
            out, (int)P, rax, rbp, nullptr, nullptr, nullptr);
    }
}

// Round 4
// 114.421 us; speedup vs baseline: 1.3814x; 1.2027x over previous
//
#include <hip/hip_runtime.h>
#include <hip/hip_bf16.h>

typedef __bf16 bf16_t;
typedef bf16_t bf16x4 __attribute__((ext_vector_type(4)));
typedef bf16_t bf16x8 __attribute__((ext_vector_type(8)));
typedef float f32x4 __attribute__((ext_vector_type(4)));

#define AS1 __attribute__((address_space(1)))
#define AS3 __attribute__((address_space(3)))

__device__ __forceinline__ void gload_lds16(const void* g, void* l) {
    __builtin_amdgcn_global_load_lds((const AS1 void*)g, (AS3 void*)l, 16, 0, 0);
}

__device__ __forceinline__ float sigmoidf_(float v) {
    return 1.0f / (1.0f + __expf(-v));
}

// ---------------- fused f32 -> bf16 convert ----------------
// Sources: x [4096x1024], protos [1024x1024], feats [2048x1024].
// Dest: contiguous ws region  XP = [x ; protos] (5120x1024) immediately followed
// by F16 = feats (2048x1024). Total 7168*1024 elems = 1,835,008 float4 chunks.
__global__ __launch_bounds__(256) void k_convert3(const float* __restrict__ x,
                                                  const float* __restrict__ pr,
                                                  const float* __restrict__ ft,
                                                  bf16_t* __restrict__ dst) {
    const int n4 = 7168 * 256;
    int i = blockIdx.x * 256 + threadIdx.x;
    const int stride = gridDim.x * 256;
    for (; i < n4; i += stride) {
        float4 v;
        if (i < 1048576) v = ((const float4*)x)[i];
        else if (i < 1310720) v = ((const float4*)pr)[i - 1048576];
        else v = ((const float4*)ft)[i - 1310720];
        bf16x4 o;
        o[0] = (bf16_t)v.x; o[1] = (bf16_t)v.y; o[2] = (bf16_t)v.z; o[3] = (bf16_t)v.w;
        ((bf16x4*)dst)[i] = o;
    }
}

// ---------------- split-K reduce + final epilogue ----------------
// out[r,c] = sum_s part_bf16[s][r,c] - pa*rsums[r] - rsums[4096+c]
// grid 2048 x 256: one 8-col chunk per thread (4096*1024/8 = 524288 = 2048*256).
__global__ __launch_bounds__(256) void k_reduce4(const bf16_t* __restrict__ part,
                                                 const float* __restrict__ rsums,
                                                 const float* __restrict__ pa,
                                                 float* __restrict__ out) {
    const long idx = (long)blockIdx.x * 256 + threadIdx.x;
    const int row = (int)(idx >> 7);
    const int c8 = ((int)idx & 127) << 3;
    float sum[8] = {};
#pragma unroll
    for (int s = 0; s < 4; ++s) {
        bf16x8 v = *(const bf16x8*)(part + (long)s * 4096 * 1024 + (long)row * 1024 + c8);
#pragma unroll
        for (int j = 0; j < 8; ++j) sum[j] += (float)v[j];
    }
    const float ra = pa[0] * rsums[row];
    const f32x4 rb0 = *(const f32x4*)&rsums[4096 + c8];
    const f32x4 rb1 = *(const f32x4*)&rsums[4096 + c8 + 4];
    f32x4 o0, o1;
#pragma unroll
    for (int j = 0; j < 4; ++j) {
        o0[j] = sum[j] - ra - rb0[j];
        o1[j] = sum[4 + j] - ra - rb1[j];
    }
    f32x4* dst = (f32x4*)(out + (long)row * 1024 + c8);
    dst[0] = o0;
    dst[1] = o1;
}

// ================= 8-phase 256x256 GEMM (m201-style, plain HIP) =================
// NT GEMM: C[m,n] = sum_k A[m,k]*B[n,k], both row-major bf16, K contiguous.
// 512 threads = 8 waves (2M x 4N); per-wave output 128x64 (8 m-frags x 4 n-frags).
// BK=64 as two 32-wide k-slices; LDS = 2buf x {A,B} x 2slice x 16KB = 128KB.
// T2 swizzle: byte ^= ((byte>>9)&1)<<5; linear LDS dest + inverse-swizzled global
// source (rule #21), swizzled ds_read. Counted vmcnt(4) twice per K-tile (T4),
// setprio around MFMA (T5), bijective XCD swizzle (T1).
// EPI 3: bf16 split-K partial write (part + bz*zstride, ld 1024).
// EPI 4: fused GEMM1 epilogue: rows<4096 -> A2=[ax|sx]; rows>=4096 -> B2=[t*bp+a*sp|b*bp];
//        plus per-row sum atomics into rsums (ax for x-rows, b*bp for proto-rows).
constexpr int SLICE = 16384;

template <int EPI>
__global__ __launch_bounds__(512, 2) void gemm8p(
    const bf16_t* __restrict__ A, const bf16_t* __restrict__ B,
    int NT, long ldab, long ldbb,
    bf16_t* __restrict__ O1, bf16_t* __restrict__ O1b,
    float* __restrict__ rsums,
    const float* __restrict__ pa, const float* __restrict__ pb, const float* __restrict__ pt,
    long zstride) {
    __shared__ char lds[131072];
    const int tid = threadIdx.x;
    const int wave = tid >> 6, lane = tid & 63;
    const int wm = wave >> 2, wn = wave & 3;

    // bijective XCD swizzle (nwg % 8 == 0 in all our launches)
    const int gx = gridDim.x, gy = gridDim.y;
    const int o = blockIdx.x + gx * (blockIdx.y + gy * blockIdx.z);
    const int cpx = (gx * gy * (int)gridDim.z) >> 3;
    const int v = (o & 7) * cpx + (o >> 3);
    const int bx = v % gx;
    const int rem = v / gx;
    const int by = rem % gy;
    const int bz = rem / gy;

    const long bm = (long)bx * 256, bn = (long)by * 256;
    const int kb0 = bz * NT * 64;
    const char* Ab = (const char*)A + bm * ldab;
    const char* Bb = (const char*)B + bn * ldbb;

    // per-lane swizzled LDS read offsets (within a 16KB slice)
    const int swzcb = ((lane >> 4) << 4) ^ (((lane >> 3) & 1) << 5);
    const int base_a = (wm * 128 + (lane & 15)) * 64 + swzcb;
    const int base_b = (wn * 64 + (lane & 15)) * 64 + swzcb;

    f32x4 acc[8][4] = {};
    bf16x8 bfrag[4];

    auto STAGE = [&](const char* gb, long ld, int kbyte, int ldsoff) {
#pragma unroll
        for (int j = 0; j < 2; ++j) {
            const int oo = (j * 512 + tid) << 4;
            const int r = oo >> 6;
            const int cb = (oo & 63) ^ (((oo >> 9) & 1) << 5);
            gload_lds16(gb + (long)r * ld + kbyte + cb, lds + ldsoff + (oo & ~1023));
        }
    };

#define KB(t, s) ((kb0 + (t) * 64 + (s) * 32) * 2)
#define LOFF(b, ab, s) ((((b) * 2 + (ab)) * 2 + (s)) * SLICE)
#define VM4 asm volatile("s_waitcnt vmcnt(4)" ::: "memory")
#define VM0 asm volatile("s_waitcnt vmcnt(0)" ::: "memory")

#define PHASE(Sl, QA, RB, PFSTMT, WAITSTMT)                                     \
    do {                                                                        \
        const int sA = LOFF(cur, 0, Sl);                                        \
        const int sB = LOFF(cur, 1, Sl);                                        \
        bf16x8 af[4];                                                           \
        _Pragma("unroll") for (int f = 0; f < 4; ++f)                           \
            af[f] = *(const bf16x8*)(lds + sA + base_a + (QA * 4 + f) * 1024);  \
        if (RB) {                                                               \
            _Pragma("unroll") for (int g = 0; g < 4; ++g)                       \
                bfrag[g] = *(const bf16x8*)(lds + sB + base_b + g * 1024);      \
        }                                                                       \
        PFSTMT;                                                                 \
        __builtin_amdgcn_sched_barrier(0);                                      \
        __builtin_amdgcn_s_barrier();                                           \
        __builtin_amdgcn_s_setprio(1);                                          \
        _Pragma("unroll") for (int f = 0; f < 4; ++f)                           \
            _Pragma("unroll") for (int g = 0; g < 4; ++g)                       \
                acc[QA * 4 + f][g] = __builtin_amdgcn_mfma_f32_16x16x32_bf16(   \
                    af[f], bfrag[g], acc[QA * 4 + f][g], 0, 0, 0);              \
        __builtin_amdgcn_s_setprio(0);                                          \
        __builtin_amdgcn_sched_barrier(0);                                      \
        WAITSTMT;                                                               \
        __builtin_amdgcn_s_barrier();                                           \
    } while (0)

    int cur = 0;
    STAGE(Ab, ldab, KB(0, 0), LOFF(0, 0, 0));
    STAGE(Bb, ldbb, KB(0, 0), LOFF(0, 1, 0));
    STAGE(Ab, ldab, KB(0, 1), LOFF(0, 0, 1));
    STAGE(Bb, ldbb, KB(0, 1), LOFF(0, 1, 1));
    VM4;
    __builtin_amdgcn_s_barrier();

    for (int t = 0; t < NT - 1; ++t) {
        const int nb = cur ^ 1;
        PHASE(0, 0, 1, STAGE(Ab, ldab, KB(t + 1, 0), LOFF(nb, 0, 0)), );
        PHASE(0, 1, 0, STAGE(Bb, ldbb, KB(t + 1, 0), LOFF(nb, 1, 0)), VM4);
        PHASE(1, 0, 1, STAGE(Ab, ldab, KB(t + 1, 1), LOFF(nb, 0, 1)), );
        PHASE(1, 1, 0, STAGE(Bb, ldbb, KB(t + 1, 1), LOFF(nb, 1, 1)), VM4);
        cur = nb;
    }
    PHASE(0, 0, 1, , );
    PHASE(0, 1, 0, , VM0);
    PHASE(1, 0, 1, , );
    PHASE(1, 1, 0, , );

#undef PHASE
#undef KB
#undef LOFF
#undef VM4
#undef VM0

    // Epilogue. C/D layout: col = lane&15, row = (lane>>4)*4 + q (m89/m91).
    const int er = (lane >> 4) << 2;
    const int ec = lane & 15;

    if constexpr (EPI == 3) {
        bf16_t* Op = O1 + (long)bz * zstride;
#pragma unroll
        for (int fg = 0; fg < 8; ++fg)
#pragma unroll
            for (int g = 0; g < 4; ++g)
#pragma unroll
                for (int q = 0; q < 4; ++q) {
                    const long r = bm + wm * 128 + fg * 16 + er + q;
                    const long c = bn + wn * 64 + g * 16 + ec;
                    Op[r * 1024 + c] = (bf16_t)acc[fg][g][q];
                }
    } else {  // EPI == 4, fused GEMM1
        const bool isX = (bx < 16);  // block-uniform
        const float va = pa[0], vb = pb[0], vt = pt[0];
        float rs[8][4];
#pragma unroll
        for (int fg = 0; fg < 8; ++fg)
#pragma unroll
            for (int q = 0; q < 4; ++q) rs[fg][q] = 0.f;

#pragma unroll
        for (int fg = 0; fg < 8; ++fg)
#pragma unroll
            for (int g = 0; g < 4; ++g)
#pragma unroll
                for (int q = 0; q < 4; ++q) {
                    const long r = bm + wm * 128 + fg * 16 + er + q;
                    const long c = bn + wn * 64 + g * 16 + ec;
                    const float vv = acc[fg][g][q];
                    const float s = sigmoidf_(vv);
                    const float prod = vv * s;
                    if (isX) {
                        O1[r * 4096 + c] = (bf16_t)prod;          // ax
                        O1[r * 4096 + 2048 + c] = (bf16_t)s;      // sx
                        rs[fg][q] += prod;
                    } else {
                        const long pr2 = r - 4096;
                        O1b[pr2 * 4096 + c] = (bf16_t)(vt * prod + va * s);  // t*bp+a*sp
                        O1b[pr2 * 4096 + 2048 + c] = (bf16_t)(vb * prod);    // b*bp
                        rs[fg][q] += vb * prod;
                    }
                }
        // 16-lane (column-group) reduce, then one atomic per row per wave
#pragma unroll
        for (int fg = 0; fg < 8; ++fg)
#pragma unroll
            for (int q = 0; q < 4; ++q) {
                float t = rs[fg][q];
                t += __shfl_xor(t, 1);
                t += __shfl_xor(t, 2);
                t += __shfl_xor(t, 4);
                t += __shfl_xor(t, 8);
                if (ec == 0) {
                    const long r = bm + wm * 128 + fg * 16 + er + q;
                    atomicAdd(&rsums[r], t);
                }
            }
    }
}

extern "C" void kernel_launch(void* const* d_in, const int* in_sizes, int n_in,
                              void* d_out, int out_size, void* d_ws, size_t ws_size,
                              hipStream_t stream) {
    const float* x = (const float*)d_in[0];       // [4096,1024]
    const float* feats = (const float*)d_in[1];   // [2048,1024]
    const float* protos = (const float*)d_in[2];  // [1024,1024]
    const float* pa = (const float*)d_in[3];
    const float* pb = (const float*)d_in[4];
    const float* pt = (const float*)d_in[5];
    float* out = (float*)d_out;                   // [4096,1024]

    constexpr long Bsz = 4096, D = 1024, F = 2048, P = 1024;

    bf16_t* XP = (bf16_t*)d_ws;                   // [5120 x 1024] = [x ; protos], 10.5 MB
    bf16_t* F16 = XP + (Bsz + P) * D;             // [2048 x 1024], 4 MB (contiguous after XP)
    bf16_t* A2 = F16 + F * D;                     // [4096 x 4096] = [ax | sx], 32 MB
    bf16_t* B2 = A2 + Bsz * 2 * F;                // [1024 x 4096] = [t*bp+a*sp | b*bp], 8 MB
    float* rsums = (float*)(B2 + P * 2 * F);      // [5120] f32, 20 KB
    bf16_t* part = (bf16_t*)(rsums + Bsz + P);    // 4 x [4096 x 1024] bf16, 32 MB

    // zero the atomic row-sum accumulator (re-done every call: deterministic)
    hipMemsetAsync(rsums, 0, (Bsz + P) * sizeof(float), stream);

    // fused convert: x -> XP[0:4096], protos -> XP[4096:5120], feats -> F16
    k_convert3<<<2048, 256, 0, stream>>>(x, protos, feats, XP);

    // fused GEMM1: [x;protos] @ feats^T  [5120 x 2048], K=1024
    //   rows < 4096 -> A2 = [ax | sx];  rows >= 4096 -> B2 = [t*bp+a*sp | b*bp]
    //   + row-sum atomics into rsums
    gemm8p<4><<<dim3((Bsz + P) / 256, F / 256, 1), 512, 0, stream>>>(
        XP, F16, (int)(D / 64), D * 2, D * 2,
        A2, B2, rsums, pa, pb, pt, 0);

    // GEMM2 split-K=4: part[z] = A2 @ B2^T over K-slice z  [4096 x 1024] bf16
    gemm8p<3><<<dim3(Bsz / 256, P / 256, 4), 512, 0, stream>>>(
        A2, B2, (int)(2 * F / 64 / 4), 2 * F * 2, 2 * F * 2,
        part, nullptr, nullptr, nullptr, nullptr, nullptr, (long)Bsz * P);

    // reduce 4 partials + subtract alpha*rowsum(ax)[r] + rowsum(beta*bp)[c]
    k_reduce4<<<2048, 256, 0, stream>>>(part, rsums, pa, out);
}